// Round 1
// baseline (489.553 us; speedup 1.0000x reference)
//
#include <hip/hip_runtime.h>

// Problem constants (from reference)
constexpr int Bn = 4096;
constexpr int Tn = 200;
constexpr int Dn = 64;
constexpr int Pn = 2;

// ---- block-wide reduce (wave64 shuffle -> LDS -> one atomic per block) ----
__device__ __forceinline__ void block_reduce_atomic(float v, float* out) {
#pragma unroll
    for (int off = 32; off > 0; off >>= 1)
        v += __shfl_down(v, off, 64);
    __shared__ float smem[8];
    const int lane = threadIdx.x & 63;
    const int wave = threadIdx.x >> 6;
    if (lane == 0) smem[wave] = v;
    __syncthreads();
    if (threadIdx.x == 0) {
        float s = 0.f;
        const int nw = (blockDim.x + 63) >> 6;
        for (int i = 0; i < nw; ++i) s += smem[i];
        atomicAdd(out, s);
    }
}

// ---- term 1: step_ahead_cov_reg (coef 1.0) ----
// sum over b of [ sum_{t<len-1,d} (cov[b,t+1,d+1]-pred[b,t,d])^2 / ((len-1)*D) ] / B
__global__ void step_kernel(const float* __restrict__ cov,
                            const float* __restrict__ preds,
                            const int* __restrict__ lengths,
                            float* __restrict__ out) {
    constexpr unsigned QPB = (Tn - 1) * (Dn / 4);      // 199*16 = 3184 quads per b
    constexpr unsigned total = (unsigned)Bn * QPB;     // 13,041,664
    const float invBD = 1.0f / ((float)Dn * (float)Bn);
    float acc = 0.f;
    const unsigned stride = gridDim.x * blockDim.x;
    for (unsigned q = blockIdx.x * blockDim.x + threadIdx.x; q < total; q += stride) {
        const unsigned b = q / QPB;                    // magic-mul div by 3184
        const unsigned r = q - b * QPB;
        const unsigned t = r >> 4;                     // 0..198
        const unsigned d = (r & 15u) << 2;             // 0,4,..,60
        const int len = lengths[b];
        if ((int)t < len - 1) {                        // masked rows: no loads at all
            const float4 p = *reinterpret_cast<const float4*>(
                preds + ((size_t)b * (Tn - 1) + t) * Dn + d);
            const float* c =
                cov + (size_t)b * Tn * (Dn + 1) + (size_t)(t + 1) * (Dn + 1) + 1 + d;
            const float d0 = c[0] - p.x;
            const float d1 = c[1] - p.y;
            const float d2 = c[2] - p.z;
            const float d3 = c[3] - p.w;
            acc += (d0 * d0 + d1 * d1 + d2 * d2 + d3 * d3) *
                   (invBD / (float)(len - 1));
        }
    }
    block_reduce_atomic(acc, out);
}

// ---- terms 2+3: theta_drift_reg (coef 0.1) + global_diff_reg (coef 0.01) ----
__global__ void theta_kernel(const float* __restrict__ pp,
                             const float* __restrict__ theta,
                             float* __restrict__ out) {
    const float r0 = 1.0f / theta[0];
    const float r1 = 1.0f / theta[1];
    const float gw = 0.01f / ((float)Bn * (float)Tn * (float)Pn);
    const float dw = 0.1f / ((float)Bn * (float)(Tn - 1) * (float)Pn);
    constexpr unsigned total = (unsigned)Bn * Tn;      // 819,200 (b,t) pairs
    float acc = 0.f;
    const unsigned stride = gridDim.x * blockDim.x;
    for (unsigned i = blockIdx.x * blockDim.x + threadIdx.x; i < total; i += stride) {
        const unsigned t = i % Tn;
        const float2 x = *reinterpret_cast<const float2*>(pp + (size_t)i * 2);
        const float g0 = x.x * r0 - 1.0f;
        const float g1 = x.y * r1 - 1.0f;
        acc += (g0 * g0 + g1 * g1) * gw;
        if (t < Tn - 1) {
            const float2 y = *reinterpret_cast<const float2*>(pp + (size_t)i * 2 + 2);
            const float e0 = x.x - y.x;
            const float e1 = x.y - y.y;
            acc += (e0 * e0 + e1 * e1) * dw;
        }
    }
    block_reduce_atomic(acc, out);
}

extern "C" void kernel_launch(void* const* d_in, const int* in_sizes, int n_in,
                              void* d_out, int out_size, void* d_ws, size_t ws_size,
                              hipStream_t stream) {
    const float* theta   = (const float*)d_in[0];  // [P]
    const float* pp      = (const float*)d_in[1];  // [B,T,P]
    // d_in[2] = hidden_states — unused by the reference
    const float* preds   = (const float*)d_in[3];  // [B,T-1,D]
    const float* cov     = (const float*)d_in[4];  // [B,T,D+1]
    const int*   lengths = (const int*)d_in[5];    // [B]
    float* out = (float*)d_out;

    // d_out is poisoned 0xAA before every launch — zero it (capture-safe).
    hipMemsetAsync(out, 0, sizeof(float), stream);

    step_kernel<<<4096, 256, 0, stream>>>(cov, preds, lengths, out);
    theta_kernel<<<1024, 256, 0, stream>>>(pp, theta, out);
}

// Round 2
// 469.442 us; speedup vs baseline: 1.0428x; 1.0428x over previous
//
#include <hip/hip_runtime.h>

// Problem constants (from reference)
constexpr int Bn = 4096;
constexpr int Tn = 200;
constexpr int Dn = 64;
constexpr int Pn = 2;

constexpr int STEP_BLOCKS  = 4096;
constexpr int THETA_BLOCKS = 1024;
constexpr int N_PARTIALS   = STEP_BLOCKS + THETA_BLOCKS;

// ---- block-wide reduce -> one value in thread 0 ----
__device__ __forceinline__ float block_reduce(float v) {
#pragma unroll
    for (int off = 32; off > 0; off >>= 1)
        v += __shfl_down(v, off, 64);
    __shared__ float smem[8];
    const int lane = threadIdx.x & 63;
    const int wave = threadIdx.x >> 6;
    if (lane == 0) smem[wave] = v;
    __syncthreads();
    float s = 0.f;
    if (threadIdx.x == 0) {
        const int nw = (blockDim.x + 63) >> 6;
        for (int i = 0; i < nw; ++i) s += smem[i];
    }
    return s;
}

// ---- term 1: step_ahead_cov_reg (coef 1.0) ----
// sum over b of [ sum_{t<len-1,d} (cov[b,t+1,d+1]-pred[b,t,d])^2 / ((len-1)*D) ] / B
__global__ void step_kernel(const float* __restrict__ cov,
                            const float* __restrict__ preds,
                            const int* __restrict__ lengths,
                            float* __restrict__ partials) {
    constexpr unsigned QPB = (Tn - 1) * (Dn / 4);      // 199*16 = 3184 quads per b
    constexpr unsigned total = (unsigned)Bn * QPB;     // 13,041,664
    const float invBD = 1.0f / ((float)Dn * (float)Bn);
    float acc = 0.f;
    const unsigned stride = gridDim.x * blockDim.x;
    for (unsigned q = blockIdx.x * blockDim.x + threadIdx.x; q < total; q += stride) {
        const unsigned b = q / QPB;                    // magic-mul div by 3184
        const unsigned r = q - b * QPB;
        const unsigned t = r >> 4;                     // 0..198
        const unsigned d = (r & 15u) << 2;             // 0,4,..,60
        const int len = lengths[b];
        if ((int)t < len - 1) {                        // masked rows: no loads at all
            const float4 p = *reinterpret_cast<const float4*>(
                preds + ((size_t)b * (Tn - 1) + t) * Dn + d);
            const float* c =
                cov + (size_t)b * Tn * (Dn + 1) + (size_t)(t + 1) * (Dn + 1) + 1 + d;
            const float d0 = c[0] - p.x;
            const float d1 = c[1] - p.y;
            const float d2 = c[2] - p.z;
            const float d3 = c[3] - p.w;
            acc += (d0 * d0 + d1 * d1 + d2 * d2 + d3 * d3) *
                   (invBD / (float)(len - 1));
        }
    }
    const float s = block_reduce(acc);
    if (threadIdx.x == 0) partials[blockIdx.x] = s;
}

// ---- terms 2+3: theta_drift_reg (coef 0.1) + global_diff_reg (coef 0.01) ----
__global__ void theta_kernel(const float* __restrict__ pp,
                             const float* __restrict__ theta,
                             float* __restrict__ partials) {
    const float r0 = 1.0f / theta[0];
    const float r1 = 1.0f / theta[1];
    const float gw = 0.01f / ((float)Bn * (float)Tn * (float)Pn);
    const float dw = 0.1f / ((float)Bn * (float)(Tn - 1) * (float)Pn);
    constexpr unsigned total = (unsigned)Bn * Tn;      // 819,200 (b,t) pairs
    float acc = 0.f;
    const unsigned stride = gridDim.x * blockDim.x;
    for (unsigned i = blockIdx.x * blockDim.x + threadIdx.x; i < total; i += stride) {
        const unsigned t = i % Tn;
        const float2 x = *reinterpret_cast<const float2*>(pp + (size_t)i * 2);
        const float g0 = x.x * r0 - 1.0f;
        const float g1 = x.y * r1 - 1.0f;
        acc += (g0 * g0 + g1 * g1) * gw;
        if (t < Tn - 1) {
            const float2 y = *reinterpret_cast<const float2*>(pp + (size_t)i * 2 + 2);
            const float e0 = x.x - y.x;
            const float e1 = x.y - y.y;
            acc += (e0 * e0 + e1 * e1) * dw;
        }
    }
    const float s = block_reduce(acc);
    if (threadIdx.x == 0) partials[STEP_BLOCKS + blockIdx.x] = s;
}

// ---- finisher: sum 5120 partials, write scalar output ----
__global__ void final_kernel(const float* __restrict__ partials,
                             float* __restrict__ out) {
    float acc = 0.f;
    for (int i = threadIdx.x; i < N_PARTIALS; i += blockDim.x)
        acc += partials[i];
    const float s = block_reduce(acc);
    if (threadIdx.x == 0) out[0] = s;
}

extern "C" void kernel_launch(void* const* d_in, const int* in_sizes, int n_in,
                              void* d_out, int out_size, void* d_ws, size_t ws_size,
                              hipStream_t stream) {
    const float* theta   = (const float*)d_in[0];  // [P]
    const float* pp      = (const float*)d_in[1];  // [B,T,P]
    // d_in[2] = hidden_states — unused by the reference
    const float* preds   = (const float*)d_in[3];  // [B,T-1,D]
    const float* cov     = (const float*)d_in[4];  // [B,T,D+1]
    const int*   lengths = (const int*)d_in[5];    // [B]
    float* out      = (float*)d_out;
    float* partials = (float*)d_ws;                // 5120 floats, written before read

    step_kernel<<<STEP_BLOCKS, 256, 0, stream>>>(cov, preds, lengths, partials);
    theta_kernel<<<THETA_BLOCKS, 256, 0, stream>>>(pp, theta, partials);
    final_kernel<<<1, 256, 0, stream>>>(partials, out);
}